// Round 1
// baseline (524.847 us; speedup 1.0000x reference)
//
#include <hip/hip_runtime.h>
#include <math.h>

#define MSG 128
#define KN 32

// ---------------------------------------------------------------------------
// Prep: M'[d][e] = (1/sqrt(128)) * sum_a Wk[a][d] * Wq[a][e]
//       c'[d]    = (1/sqrt(128)) * sum_a Wk[a][d] * bq[a]
// Q·bk is constant across neighbors -> cancels in softmax, dropped.
// ---------------------------------------------------------------------------
__global__ void gac_prep(const float* __restrict__ Wq, const float* __restrict__ bq,
                         const float* __restrict__ Wk,
                         float* __restrict__ Mp, float* __restrict__ cp) {
    const float inv_scale = 0.088388347648318440f; // 1/sqrt(128)
    const int d = blockIdx.x;   // 0..127
    const int e = threadIdx.x;  // 0..127
    float acc = 0.f;
#pragma unroll 8
    for (int a = 0; a < 128; ++a)
        acc = fmaf(Wk[a * 128 + d], Wq[a * 128 + e], acc);
    Mp[d * 128 + e] = acc * inv_scale;

    if (threadIdx.x < 64) {  // wave 0 computes c'[d]
        const int l = threadIdx.x;
        float p = Wk[l * 128 + d] * bq[l] + Wk[(l + 64) * 128 + d] * bq[l + 64];
#pragma unroll
        for (int off = 32; off; off >>= 1) p += __shfl_down(p, off, 64);
        if (l == 0) cp[d] = p * inv_scale;
    }
}

// ---------------------------------------------------------------------------
// Main fused kernel: per node
//   q'' = M' q + c'           (register-resident M', 256 threads: row r, half h)
//   s_k = q''. x_k            (x_k read ONCE from HBM into regs, shfl reduce)
//   att = softmax(s)
//   ctx = sum att_k x_k       (from the same registers)
//   out = Wv ctx + bv         (register-resident Wv)
// ---------------------------------------------------------------------------
__global__ __launch_bounds__(256, 2)
void gac_main(const float* __restrict__ query,
              const float* __restrict__ nbr,
              const float* __restrict__ Mp,
              const float* __restrict__ cp,
              const float* __restrict__ Wv,
              const float* __restrict__ bv,
              float* __restrict__ out,
              int N, int npb) {
    __shared__ __align__(16) float qbuf[128];
    __shared__ __align__(16) float q2[128];
    __shared__ __align__(16) float part[2][128];
    __shared__ __align__(16) float partw[4][128];
    __shared__ float scores_s[32];
    __shared__ float att_s[32];
    __shared__ __align__(16) float ctx2[128];

    const int t = threadIdx.x;
    const int r = t & 127;   // output row this thread owns
    const int h = t >> 7;    // which half of the inner dim (0/1)
    const int w = t >> 6;    // wave id 0..3
    const int l = t & 63;    // lane id

    // Register-resident weights: thread (r,h) owns M'[r][64h..64h+63], Wv[r][64h..]
    float4 wA[16], wV[16];
    {
        const float4* a = (const float4*)(Mp + r * 128 + h * 64);
        const float4* v = (const float4*)(Wv + r * 128 + h * 64);
#pragma unroll
        for (int i = 0; i < 16; ++i) { wA[i] = a[i]; wV[i] = v[i]; }
    }
    const float c_r  = (h == 0) ? cp[r] : 0.f;
    const float bv_r = (h == 0) ? bv[r] : 0.f;

    const int n0 = blockIdx.x * npb;
    const int n1 = min(n0 + npb, N);
    if (n0 >= n1) return;

    // Each wave w handles neighbors k = w + 4j (j=0..7); lane l holds x[k][2l..2l+1]
    float2 xv[8];
    {
        const float* x = nbr + (size_t)n0 * KN * MSG;
#pragma unroll
        for (int j = 0; j < 8; ++j)
            xv[j] = ((const float2*)(x + (w + 4 * j) * MSG))[l];
    }

    for (int n = n0; n < n1; ++n) {
        // stage q
        if (t < 32)
            ((float4*)qbuf)[t] = ((const float4*)(query + (size_t)n * MSG))[t];
        __syncthreads();

        // phase A: q'' = M' q + c'   (j-split across h, combine via LDS)
        float acc = c_r;
        {
            const float4* q4 = (const float4*)(qbuf + h * 64);
#pragma unroll
            for (int i = 0; i < 16; ++i) {
                float4 qv = q4[i];
                acc = fmaf(wA[i].x, qv.x, acc);
                acc = fmaf(wA[i].y, qv.y, acc);
                acc = fmaf(wA[i].z, qv.z, acc);
                acc = fmaf(wA[i].w, qv.w, acc);
            }
        }
        part[h][r] = acc;
        __syncthreads();
        if (t < 128) q2[t] = part[0][t] + part[1][t];
        __syncthreads();

        // phase B: scores (lane l holds q''[2l], q''[2l+1])
        const float2 qq = ((const float2*)q2)[l];
#pragma unroll
        for (int j = 0; j < 8; ++j) {
            float p = xv[j].x * qq.x + xv[j].y * qq.y;
#pragma unroll
            for (int off = 32; off; off >>= 1) p += __shfl_down(p, off, 64);
            if (l == 0) scores_s[w + 4 * j] = p;
        }
        __syncthreads();

        // softmax over 32 neighbors (lanes 0..31 of wave 0)
        if (t < 32) {
            float s = scores_s[t];
            float m = s;
#pragma unroll
            for (int off = 16; off; off >>= 1) m = fmaxf(m, __shfl_xor(m, off, 64));
            float e = __expf(s - m);
            float sum = e;
#pragma unroll
            for (int off = 16; off; off >>= 1) sum += __shfl_xor(sum, off, 64);
            att_s[t] = e / sum;
        }
        __syncthreads();

        // ctx partials straight from the x registers
        float2 pc = make_float2(0.f, 0.f);
#pragma unroll
        for (int j = 0; j < 8; ++j) {
            float a = att_s[w + 4 * j];
            pc.x = fmaf(a, xv[j].x, pc.x);
            pc.y = fmaf(a, xv[j].y, pc.y);
        }
        ((float2*)partw[w])[l] = pc;

        // prefetch next node's neighbor tile (xv is dead now)
        if (n + 1 < n1) {
            const float* x = nbr + (size_t)(n + 1) * KN * MSG;
#pragma unroll
            for (int j = 0; j < 8; ++j)
                xv[j] = ((const float2*)(x + (w + 4 * j) * MSG))[l];
        }
        __syncthreads();
        if (t < 128) ctx2[t] = partw[0][t] + partw[1][t] + partw[2][t] + partw[3][t];
        __syncthreads();

        // phase C: out = Wv ctx + bv
        float acco = bv_r;
        {
            const float4* c4 = (const float4*)(ctx2 + h * 64);
#pragma unroll
            for (int i = 0; i < 16; ++i) {
                float4 cv = c4[i];
                acco = fmaf(wV[i].x, cv.x, acco);
                acco = fmaf(wV[i].y, cv.y, acco);
                acco = fmaf(wV[i].z, cv.z, acco);
                acco = fmaf(wV[i].w, cv.w, acco);
            }
        }
        part[h][r] = acco;
        __syncthreads();
        if (t < 128) out[(size_t)n * MSG + t] = part[0][t] + part[1][t];
        // no trailing barrier needed: next write to qbuf/part is separated by the
        // stage barrier at loop top; all cross-phase reads above are fenced.
    }
}

extern "C" void kernel_launch(void* const* d_in, const int* in_sizes, int n_in,
                              void* d_out, int out_size, void* d_ws, size_t ws_size,
                              hipStream_t stream) {
    const float* query = (const float*)d_in[0];
    const float* nbr   = (const float*)d_in[1];
    const float* Wq    = (const float*)d_in[2];
    const float* bq    = (const float*)d_in[3];
    const float* Wk    = (const float*)d_in[4];
    /* bk = d_in[5] unused: Q·bk is constant across k -> softmax-invariant */
    const float* Wv    = (const float*)d_in[6];
    const float* bv    = (const float*)d_in[7];
    float* out = (float*)d_out;

    float* Mp = (float*)d_ws;        // 128*128 floats
    float* cp = Mp + 128 * 128;      // 128 floats

    const int N = in_sizes[0] / MSG;

    gac_prep<<<128, 128, 0, stream>>>(Wq, bq, Wk, Mp, cp);

    const int npb = 40;                      // nodes per block
    const int grid = (N + npb - 1) / npb;    // 500 blocks @ N=20000
    gac_main<<<grid, 256, 0, stream>>>(query, nbr, Mp, cp, Wv, bv, out, N, npb);
}

// Round 2
// 502.520 us; speedup vs baseline: 1.0444x; 1.0444x over previous
//
#include <hip/hip_runtime.h>
#include <math.h>

#define MSG 128
#define KN 32

// ---------------------------------------------------------------------------
// Prep: M'[d][e] = (1/sqrt(128)) * sum_a Wk[a][d] * Wq[a][e]
//       c'[d]    = (1/sqrt(128)) * sum_a Wk[a][d] * bq[a]
// Q·bk is constant across neighbors -> cancels in softmax, dropped.
// ---------------------------------------------------------------------------
__global__ void gac_prep(const float* __restrict__ Wq, const float* __restrict__ bq,
                         const float* __restrict__ Wk,
                         float* __restrict__ Mp, float* __restrict__ cp) {
    const float inv_scale = 0.088388347648318440f; // 1/sqrt(128)
    const int d = blockIdx.x;   // 0..127
    const int e = threadIdx.x;  // 0..127
    float acc = 0.f;
#pragma unroll 8
    for (int a = 0; a < 128; ++a)
        acc = fmaf(Wk[a * 128 + d], Wq[a * 128 + e], acc);
    Mp[d * 128 + e] = acc * inv_scale;

    if (threadIdx.x < 64) {  // wave 0 computes c'[d]
        const int l = threadIdx.x;
        float p = Wk[l * 128 + d] * bq[l] + Wk[(l + 64) * 128 + d] * bq[l + 64];
#pragma unroll
        for (int off = 32; off; off >>= 1) p += __shfl_down(p, off, 64);
        if (l == 0) cp[d] = p * inv_scale;
    }
}

// ---------------------------------------------------------------------------
// Batched 128x128 matvec: out[n][r] = sum_e W[r][e] * in[n][e] + b[r]
// One block = 16 nodes. Thread (r,h) owns W[r][64h..64h+63] in registers.
// Used for Q'' = q @ M'^T + c'  and  out = ctx @ Wv^T + bv.
// ---------------------------------------------------------------------------
__global__ __launch_bounds__(256, 2)
void gac_matvec16(const float* __restrict__ in, const float* __restrict__ W,
                  const float* __restrict__ b, float* __restrict__ out, int N) {
    __shared__ __align__(16) float qs[16 * 128];        // 8 KB staged inputs
    __shared__ __align__(16) float part[2 * 16 * 128];  // 16 KB partials
    const int t = threadIdx.x;
    const int r = t & 127;
    const int h = t >> 7;

    float4 wreg[16];
    {
        const float4* wp = (const float4*)(W + r * 128 + h * 64);
#pragma unroll
        for (int i = 0; i < 16; ++i) wreg[i] = wp[i];
    }
    const float br = (h == 0) ? b[r] : 0.f;

    const int n0 = blockIdx.x * 16;
    const size_t maxf4 = (size_t)N * (MSG / 4) - 1;  // clamp for tail safety
    {
        const float4* src = (const float4*)in;
        size_t i0 = (size_t)n0 * 32 + t;
        size_t i1 = i0 + 256;
        ((float4*)qs)[t]       = src[i0 > maxf4 ? maxf4 : i0];
        ((float4*)qs)[t + 256] = src[i1 > maxf4 ? maxf4 : i1];
    }
    __syncthreads();

    float acc[16];
#pragma unroll
    for (int j = 0; j < 16; ++j) acc[j] = br;
#pragma unroll
    for (int i = 0; i < 16; ++i) {
        const float4 w4 = wreg[i];
#pragma unroll
        for (int j = 0; j < 16; ++j) {
            const float4 q4 = ((const float4*)(qs + j * 128 + h * 64))[i];  // broadcast
            acc[j] = fmaf(w4.x, q4.x, acc[j]);
            acc[j] = fmaf(w4.y, q4.y, acc[j]);
            acc[j] = fmaf(w4.z, q4.z, acc[j]);
            acc[j] = fmaf(w4.w, q4.w, acc[j]);
        }
    }
#pragma unroll
    for (int j = 0; j < 16; ++j) part[h * 2048 + j * 128 + r] = acc[j];
    __syncthreads();

#pragma unroll
    for (int i = 0; i < 8; ++i) {
        const int e = t + 256 * i;                 // flat element in this 16-node chunk
        const int n = n0 + (e >> 7);
        if (n < N) out[(size_t)n0 * MSG + e] = part[e] + part[2048 + e];
    }
}

// ---------------------------------------------------------------------------
// Attention + context: one WAVE per node, no LDS, no barriers.
// Lane l holds element pair (2l, 2l+1) of ALL 32 neighbors (64 VGPRs):
//   s_k  = sum_l xv[k]·qq        (shfl_xor tree, every lane gets s_k)
//   att  = softmax over k        (lane l owns k = l&31, duplicated halves)
//   ctx  = sum_k att_k xv[k]     (pure per-lane FMA — no cross-lane at all)
// ---------------------------------------------------------------------------
__global__ __launch_bounds__(256, 4)
void gac_attn(const float* __restrict__ Qpp, const float* __restrict__ nbr,
              float* __restrict__ ctx, int N) {
    const int t = threadIdx.x;
    const int w = t >> 6;
    const int l = t & 63;
    const int n = blockIdx.x * 4 + w;
    if (n >= N) return;

    const float* x = nbr + (size_t)n * KN * MSG;
    float2 xv[KN];
#pragma unroll
    for (int k = 0; k < KN; ++k)
        xv[k] = ((const float2*)(x + k * MSG))[l];
    const float2 qq = ((const float2*)(Qpp + (size_t)n * MSG))[l];

    // scores: 32 butterfly trees; lane l keeps s for k == (l&31)
    float s = 0.f;
    const int myk = l & 31;
#pragma unroll
    for (int k = 0; k < KN; ++k) {
        float p = fmaf(xv[k].y, qq.y, xv[k].x * qq.x);
#pragma unroll
        for (int off = 32; off; off >>= 1) p += __shfl_xor(p, off, 64);
        if (myk == k) s = p;
    }

    // softmax over the 32 values (each 32-lane half holds all 32, once each)
    float m = s;
#pragma unroll
    for (int off = 16; off; off >>= 1) m = fmaxf(m, __shfl_xor(m, off, 64));
    const float e = __expf(s - m);
    float sum = e;
#pragma unroll
    for (int off = 16; off; off >>= 1) sum += __shfl_xor(sum, off, 64);
    const float a = e / sum;  // att for k = l&31 (dup in both halves)

    // context: broadcast att_k from lane k, accumulate per-lane pair
    float2 c = make_float2(0.f, 0.f);
#pragma unroll
    for (int k = 0; k < KN; ++k) {
        const float ak = __shfl(a, k, 64);
        c.x = fmaf(ak, xv[k].x, c.x);
        c.y = fmaf(ak, xv[k].y, c.y);
    }
    ((float2*)(ctx + (size_t)n * MSG))[l] = c;
}

extern "C" void kernel_launch(void* const* d_in, const int* in_sizes, int n_in,
                              void* d_out, int out_size, void* d_ws, size_t ws_size,
                              hipStream_t stream) {
    const float* query = (const float*)d_in[0];
    const float* nbr   = (const float*)d_in[1];
    const float* Wq    = (const float*)d_in[2];
    const float* bq    = (const float*)d_in[3];
    const float* Wk    = (const float*)d_in[4];
    /* bk = d_in[5] unused: Q·bk is constant across k -> softmax-invariant */
    const float* Wv    = (const float*)d_in[6];
    const float* bv    = (const float*)d_in[7];
    float* out = (float*)d_out;

    const int N = in_sizes[0] / MSG;

    float* Mp   = (float*)d_ws;            // 128*128
    float* cp   = Mp + 128 * 128;          // 128
    float* Qpp  = cp + 128;                // N*128  (16B-aligned: off 16512 floats)
    float* ctxb = Qpp + (size_t)N * MSG;   // N*128

    gac_prep<<<128, 128, 0, stream>>>(Wq, bq, Wk, Mp, cp);

    const int gmv = (N + 15) / 16;  // 1250
    gac_matvec16<<<gmv, 256, 0, stream>>>(query, Mp, cp, Qpp, N);

    const int gat = (N + 3) / 4;    // 5000
    gac_attn<<<gat, 256, 0, stream>>>(Qpp, nbr, ctxb, N);

    gac_matvec16<<<gmv, 256, 0, stream>>>(ctxb, Wv, bv, out, N);
}

// Round 3
// 502.090 us; speedup vs baseline: 1.0453x; 1.0009x over previous
//
#include <hip/hip_runtime.h>
#include <math.h>

#define MSG 128
#define KN 32

// ---------------------------------------------------------------------------
// Prep: M'[d][e] = (1/sqrt(128)) * sum_a Wk[a][d] * Wq[a][e]
//       c'[d]    = (1/sqrt(128)) * sum_a Wk[a][d] * bq[a]
// Q·bk is constant across neighbors -> cancels in softmax, dropped.
// ---------------------------------------------------------------------------
__global__ void gac_prep(const float* __restrict__ Wq, const float* __restrict__ bq,
                         const float* __restrict__ Wk,
                         float* __restrict__ Mp, float* __restrict__ cp) {
    const float inv_scale = 0.088388347648318440f; // 1/sqrt(128)
    const int d = blockIdx.x;   // 0..127
    const int e = threadIdx.x;  // 0..127
    float acc = 0.f;
#pragma unroll 8
    for (int a = 0; a < 128; ++a)
        acc = fmaf(Wk[a * 128 + d], Wq[a * 128 + e], acc);
    Mp[d * 128 + e] = acc * inv_scale;

    if (threadIdx.x < 64) {  // wave 0 computes c'[d]
        const int l = threadIdx.x;
        float p = Wk[l * 128 + d] * bq[l] + Wk[(l + 64) * 128 + d] * bq[l + 64];
#pragma unroll
        for (int off = 32; off; off >>= 1) p += __shfl_down(p, off, 64);
        if (l == 0) cp[d] = p * inv_scale;
    }
}

// ---------------------------------------------------------------------------
// Fully fused: one block = 16 nodes.
//   P2: q'' = q @ M'^T + c'   (M' rows phase-scoped in regs, h-split)
//   P3: wave-per-node attention+context, barrier-free inside the phase,
//       neighbor row read ONCE from HBM into regs (64 VGPR/lane)
//   P4: out = ctx @ Wv^T + bv (Wv rows phase-scoped in regs)
// Register lifetimes wA -> xv -> wV are disjoint: peak ~110 VGPR, 4 waves/EU.
// LDS 32 KB -> 4 blocks/CU = 16 waves/CU for latency hiding.
// Saves the Qpp/ctx HBM round-trips (41 MB) and 2 kernel launches.
// ---------------------------------------------------------------------------
__global__ __launch_bounds__(256, 4)
void gac_fused(const float* __restrict__ query,
               const float* __restrict__ nbr,
               const float* __restrict__ Mp,
               const float* __restrict__ cp,
               const float* __restrict__ Wv,
               const float* __restrict__ bv,
               float* __restrict__ out, int N) {
    __shared__ __align__(16) float bufA[16 * 128];      // q, then ctx (8 KB)
    __shared__ __align__(16) float q2[16 * 128];        // q''       (8 KB)
    __shared__ __align__(16) float part[2 * 16 * 128];  // h-partials (16 KB)

    const int t = threadIdx.x;
    const int r = t & 127;   // matvec output row
    const int h = t >> 7;    // inner-dim half
    const int w = t >> 6;    // wave 0..3
    const int l = t & 63;    // lane

    const int n0 = blockIdx.x * 16;
    const size_t maxf4 = (size_t)N * 32 - 1;

    // ---- stage q for 16 nodes (coalesced float4) ----
    {
        const float4* src = (const float4*)query;
        size_t i0 = (size_t)n0 * 32 + t;
        size_t i1 = i0 + 256;
        ((float4*)bufA)[t]       = src[i0 > maxf4 ? maxf4 : i0];
        ((float4*)bufA)[t + 256] = src[i1 > maxf4 ? maxf4 : i1];
    }
    __syncthreads();  // B1

    // ---- P2: q'' = M' q + c' ----
    {
        float4 wA[16];
        const float4* wp = (const float4*)(Mp + r * 128 + h * 64);
#pragma unroll
        for (int i = 0; i < 16; ++i) wA[i] = wp[i];
        const float br = (h == 0) ? cp[r] : 0.f;
        float acc[16];
#pragma unroll
        for (int j = 0; j < 16; ++j) acc[j] = br;
#pragma unroll
        for (int i = 0; i < 16; ++i) {
            const float4 w4 = wA[i];
#pragma unroll
            for (int j = 0; j < 16; ++j) {
                const float4 q4 = ((const float4*)(bufA + j * 128 + h * 64))[i]; // LDS broadcast
                acc[j] = fmaf(w4.x, q4.x, acc[j]);
                acc[j] = fmaf(w4.y, q4.y, acc[j]);
                acc[j] = fmaf(w4.z, q4.z, acc[j]);
                acc[j] = fmaf(w4.w, q4.w, acc[j]);
            }
        }
#pragma unroll
        for (int j = 0; j < 16; ++j) part[h * 2048 + j * 128 + r] = acc[j];
    }
    __syncthreads();  // B2
#pragma unroll
    for (int i = 0; i < 8; ++i) {
        const int e = t + 256 * i;
        q2[e] = part[e] + part[2048 + e];
    }
    __syncthreads();  // B3

    // ---- P3: attention + context, wave-per-node, 4 nodes per wave ----
#pragma unroll 1     // keep xv footprint to a single node
    for (int jj = 0; jj < 4; ++jj) {
        const int ln = 4 * w + jj;
        int n = n0 + ln;
        if (n >= N) n = N - 1;               // clamped garbage, store guarded later
        const float* x = nbr + (size_t)n * KN * MSG;
        float2 xv[KN];
#pragma unroll
        for (int k = 0; k < KN; ++k)
            xv[k] = ((const float2*)(x + k * MSG))[l];
        const float2 qq = ((const float2*)(q2 + ln * 128))[l];

        // scores: butterfly tree per k; lane l keeps s for k == (l&31)
        float s = 0.f;
        const int myk = l & 31;
#pragma unroll
        for (int k = 0; k < KN; ++k) {
            float p = fmaf(xv[k].y, qq.y, xv[k].x * qq.x);
#pragma unroll
            for (int off = 32; off; off >>= 1) p += __shfl_xor(p, off, 64);
            if (myk == k) s = p;
        }
        // softmax over 32 (duplicated in both 32-lane halves)
        float m = s;
#pragma unroll
        for (int off = 16; off; off >>= 1) m = fmaxf(m, __shfl_xor(m, off, 64));
        const float e = __expf(s - m);
        float sum = e;
#pragma unroll
        for (int off = 16; off; off >>= 1) sum += __shfl_xor(sum, off, 64);
        const float a = e / sum;
        // context (no cross-lane needed in this layout)
        float2 c = make_float2(0.f, 0.f);
#pragma unroll
        for (int k = 0; k < KN; ++k) {
            const float ak = __shfl(a, k, 64);
            c.x = fmaf(ak, xv[k].x, c.x);
            c.y = fmaf(ak, xv[k].y, c.y);
        }
        ((float2*)(bufA + ln * 128))[l] = c;  // q is dead; reuse bufA for ctx
    }
    __syncthreads();  // B4

    // ---- P4: out = Wv ctx + bv ----
    {
        float4 wV[16];
        const float4* wp = (const float4*)(Wv + r * 128 + h * 64);
#pragma unroll
        for (int i = 0; i < 16; ++i) wV[i] = wp[i];
        const float br = (h == 0) ? bv[r] : 0.f;
        float acc[16];
#pragma unroll
        for (int j = 0; j < 16; ++j) acc[j] = br;
#pragma unroll
        for (int i = 0; i < 16; ++i) {
            const float4 w4 = wV[i];
#pragma unroll
            for (int j = 0; j < 16; ++j) {
                const float4 c4 = ((const float4*)(bufA + j * 128 + h * 64))[i];
                acc[j] = fmaf(w4.x, c4.x, acc[j]);
                acc[j] = fmaf(w4.y, c4.y, acc[j]);
                acc[j] = fmaf(w4.z, c4.z, acc[j]);
                acc[j] = fmaf(w4.w, c4.w, acc[j]);
            }
        }
#pragma unroll
        for (int j = 0; j < 16; ++j) part[h * 2048 + j * 128 + r] = acc[j];
    }
    __syncthreads();  // B5
#pragma unroll
    for (int i = 0; i < 8; ++i) {
        const int e = t + 256 * i;
        const size_t idx = (size_t)n0 * 128 + e;
        if (idx < (size_t)N * 128) out[idx] = part[e] + part[2048 + e];
    }
}

extern "C" void kernel_launch(void* const* d_in, const int* in_sizes, int n_in,
                              void* d_out, int out_size, void* d_ws, size_t ws_size,
                              hipStream_t stream) {
    const float* query = (const float*)d_in[0];
    const float* nbr   = (const float*)d_in[1];
    const float* Wq    = (const float*)d_in[2];
    const float* bq    = (const float*)d_in[3];
    const float* Wk    = (const float*)d_in[4];
    /* bk = d_in[5] unused: Q·bk is constant across k -> softmax-invariant */
    const float* Wv    = (const float*)d_in[6];
    const float* bv    = (const float*)d_in[7];
    float* out = (float*)d_out;

    const int N = in_sizes[0] / MSG;

    float* Mp = (float*)d_ws;       // 128*128
    float* cp = Mp + 128 * 128;     // 128

    gac_prep<<<128, 128, 0, stream>>>(Wq, bq, Wk, Mp, cp);

    const int grid = (N + 15) / 16;  // 1250
    gac_fused<<<grid, 256, 0, stream>>>(query, nbr, Mp, cp, Wv, bv, out, N);
}